// Round 4
// baseline (202.363 us; speedup 1.0000x reference)
//
#include <hip/hip_runtime.h>

// FWEnergyGAD: element-wise double-well energy + forces + GAD direction +
// 2x2 Hessian eigendecomposition (closed form).
//
// Outputs concatenated flat in return order (n = B):
//   [0,     n)   energy
//   [n,    3n)   forces      (B,2)
//   [3n,   5n)   energy_grad (B,2)
//   [5n,   9n)   hessian     (B,2,2)
//   [9n,  10n)   eigenval 0  (smaller)
//   [10n, 11n)   eigenval 1  (larger)
//
// v5: grid-stride PERSISTENT kernel. Evidence: the harness's own
// fillBuffer sustains 6.7 TB/s at 9.4% occupancy via a persistent
// grid-stride loop, while our one-shot kernels (v1-v4) are stuck at
// ~2.4 TB/s regardless of burst size (v3), ILP shape (v2), or ALU cost
// (v4). Perf anti-correlates with per-wave-exit store count: one-shot
// waves pay a store-drain + relaunch tail per point-batch, 65536 times.
// v5 keeps v1's exact per-instruction across-wave access shape (that was
// never the problem) but runs 2048 blocks x 256 threads, 8 points/thread
// at stride gridDim*blockDim: input loads batched up-front (one amortized
// HBM latency), stores pipeline continuously from live waves, drain tail
// paid once per wave instead of once per point.

typedef float f2v __attribute__((ext_vector_type(2)));
typedef float f4v __attribute__((ext_vector_type(4)));

#define PPT 8          // points per thread
#define BLOCK 256

__global__ __launch_bounds__(BLOCK, 4) void fw_energy_gad_kernel(
    const f2v* __restrict__ in, float* __restrict__ out, int n) {
    const float BETA = 0.1f;

    size_t N = (size_t)n;
    float* e_out  = out;
    f2v*   f_out  = (f2v*)(out + N);
    f2v*   g_out  = (f2v*)(out + 3 * N);
    f4v*   h_out  = (f4v*)(out + 5 * N);
    float* l0_out = out + 9 * N;
    float* l1_out = out + 10 * N;

    int S  = gridDim.x * blockDim.x;                 // total threads
    int i0 = blockIdx.x * blockDim.x + threadIdx.x;

    // Batch-issue all input loads first: 8 independent global_load_dwordx2
    // in flight -> one amortized HBM latency per wave-iteration-set.
    f2v p[PPT];
    #pragma unroll
    for (int k = 0; k < PPT; ++k) {
        int i = i0 + k * S;
        if (i < n) p[k] = in[i];
    }

    #pragma unroll
    for (int k = 0; k < PPT; ++k) {
        int i = i0 + k * S;
        if (i >= n) continue;

        float u = p[k].x - 0.5f;
        float v = p[k].y - 0.5f;
        float uu = u * u;
        float vv = v * v;
        float a = uu - 1.0f;   // u^2 - 1
        float b = vv - 1.0f;   // v^2 - 1

        float energy = a * a + b * b + BETA * u * v;

        float gx = 4.0f * u * a + BETA * v;
        float gy = 4.0f * v * b + BETA * u;
        float fx = -gx;
        float fy = -gy;

        float hxx = 12.0f * uu - 4.0f;
        float hyy = 12.0f * vv - 4.0f;
        // hxy = BETA (constant)

        // 2x2 symmetric eigendecomposition, closed form.
        float d = 0.5f * (hxx - hyy);
        float m = 0.5f * (hxx + hyy);
        float r = __builtin_amdgcn_sqrtf(d * d + BETA * BETA);  // r >= 0.1
        float l0 = m - r;                    // smaller eigenvalue
        float l1 = m + r;                    // larger eigenvalue

        // Eigenvector of l0; select-branch chosen to avoid cancellation
        // (|d| can be ~380 vs hxy=0.1; wrong branch computes r-|d|:
        // catastrophic in fp32).
        bool pos = (d >= 0.0f);
        float wx = pos ? BETA : (d - r);
        float wy = pos ? -(d + r) : BETA;
        float n2 = wx * wx + wy * wy;        // >= 0.01

        // gad = -f + 2 (f.w_hat) w_hat ; sign of w irrelevant (quadratic).
        float fd = fx * wx + fy * wy;
        float s = (2.0f * fd) * __builtin_amdgcn_rcpf(n2);
        float gadx = -fx + s * wx;
        float gady = -fy + s * wy;

        float prod = l0 * l1;                // reference's eigval product
        float g2 = gadx * gadx + gady * gady;   // gmag^2; gmag<1 <=> g2<1
        if (prod > 0.0f && g2 < 1.0f) {
            float inv = __builtin_amdgcn_rsqf(fmaxf(g2, 1e-60f));
            gadx *= inv;
            gady *= inv;
        }
        // TAU = 1.0 -> energy_grad == gad

        e_out[i] = energy;
        f2v fo; fo.x = fx; fo.y = fy;
        f_out[i] = fo;
        f2v go; go.x = gadx; go.y = gady;
        g_out[i] = go;
        f4v ho; ho.x = hxx; ho.y = BETA; ho.z = BETA; ho.w = hyy;
        h_out[i] = ho;
        l0_out[i] = l0;
        l1_out[i] = l1;
    }
}

extern "C" void kernel_launch(void* const* d_in, const int* in_sizes, int n_in,
                              void* d_out, int out_size, void* d_ws, size_t ws_size,
                              hipStream_t stream) {
    const f2v* in = (const f2v*)d_in[0];
    float* out = (float*)d_out;
    int n = in_sizes[0] / 2;   // B points, each (x, y)

    int grid = (n + BLOCK * PPT - 1) / (BLOCK * PPT);   // 2048 for B=4.19M
    if (grid < 1) grid = 1;
    fw_energy_gad_kernel<<<grid, BLOCK, 0, stream>>>(in, out, n);
}

// Round 5
// 201.909 us; speedup vs baseline: 1.0022x; 1.0022x over previous
//
#include <hip/hip_runtime.h>

// FWEnergyGAD: element-wise double-well energy + forces + GAD direction +
// 2x2 Hessian eigendecomposition (closed form).
//
// Outputs concatenated flat in return order (n = B):
//   [0,     n)   energy
//   [n,    3n)   forces      (B,2)
//   [3n,   5n)   energy_grad (B,2)
//   [5n,   9n)   hessian     (B,2,2)
//   [9n,  10n)   eigenval 0  (smaller)
//   [10n, 11n)   eigenval 1  (larger)
//
// v6 = v4 (1 pt/thread, best-known structure) + NONTEMPORAL stores ONLY.
// Single-variable A/B vs v4 (198.2 us total).
// Theory: timed region = poison-fill(738MB) -> kernel. The fill leaves the
// 256MiB Infinity Cache full of DIRTY poison lines. Our cached stores
// allocate in L3 and force ~185MB of poison writebacks onto the kernel's
// critical path (plus thrashed-input re-reads) -> every structural variant
// (v1-v5, 88-97us) was stuck because the cost is cache-state debt, not the
// instruction stream. NT stores don't allocate -> poison stays in L3 and is
// absorbed for free by the next fill's overwrite; our 184.5MB streams at
// fill-like efficiency. v2 did NOT refute NT: it confounded NT with the
// split-half layout (v3 showed that structure class costs ~8us alone).

typedef float f2v __attribute__((ext_vector_type(2)));
typedef float f4v __attribute__((ext_vector_type(4)));

__global__ __launch_bounds__(256, 8) void fw_energy_gad_kernel(
    const f2v* __restrict__ in, float* __restrict__ out, int n) {
    int i = blockIdx.x * blockDim.x + threadIdx.x;
    if (i >= n) return;

    const float BETA = 0.1f;

    f2v p = in[i];
    float u = p.x - 0.5f;
    float v = p.y - 0.5f;
    float uu = u * u;
    float vv = v * v;
    float a = uu - 1.0f;   // u^2 - 1
    float b = vv - 1.0f;   // v^2 - 1

    float energy = a * a + b * b + BETA * u * v;

    float gx = 4.0f * u * a + BETA * v;
    float gy = 4.0f * v * b + BETA * u;
    float fx = -gx;
    float fy = -gy;

    float hxx = 12.0f * uu - 4.0f;
    float hyy = 12.0f * vv - 4.0f;
    // hxy = BETA (constant)

    // 2x2 symmetric eigendecomposition, closed form.
    float d = 0.5f * (hxx - hyy);
    float m = 0.5f * (hxx + hyy);
    float r = __builtin_amdgcn_sqrtf(d * d + BETA * BETA);  // r >= 0.1
    float l0 = m - r;                        // smaller eigenvalue
    float l1 = m + r;                        // larger eigenvalue

    // Eigenvector of l0, select-branch chosen to avoid cancellation (|d|
    // can be ~380 vs hxy=0.1; wrong branch computes r-|d|: catastrophic).
    bool pos = (d >= 0.0f);
    float wx = pos ? BETA : (d - r);
    float wy = pos ? -(d + r) : BETA;
    float n2 = wx * wx + wy * wy;            // >= 0.01

    // gad = -f + 2 (f.w_hat) w_hat ; sign of w irrelevant (quadratic).
    float fd = fx * wx + fy * wy;
    float s = (2.0f * fd) * __builtin_amdgcn_rcpf(n2);
    float gadx = -fx + s * wx;
    float gady = -fy + s * wy;

    float prod = l0 * l1;                    // matches reference's product
    float g2 = gadx * gadx + gady * gady;    // gmag^2; gmag<1 <=> g2<1
    if (prod > 0.0f && g2 < 1.0f) {
        float inv = __builtin_amdgcn_rsqf(fmaxf(g2, 1e-60f));
        gadx *= inv;
        gady *= inv;
    }
    // TAU = 1.0 -> energy_grad == gad

    size_t N = (size_t)n;
    float* e_out  = out;
    f2v*   f_out  = (f2v*)(out + N);
    f2v*   g_out  = (f2v*)(out + 3 * N);
    f4v*   h_out  = (f4v*)(out + 5 * N);
    float* l0_out = out + 9 * N;
    float* l1_out = out + 10 * N;

    __builtin_nontemporal_store(energy, e_out + i);
    f2v fo; fo.x = fx; fo.y = fy;
    __builtin_nontemporal_store(fo, f_out + i);
    f2v go; go.x = gadx; go.y = gady;
    __builtin_nontemporal_store(go, g_out + i);
    f4v ho; ho.x = hxx; ho.y = BETA; ho.z = BETA; ho.w = hyy;
    __builtin_nontemporal_store(ho, h_out + i);
    __builtin_nontemporal_store(l0, l0_out + i);
    __builtin_nontemporal_store(l1, l1_out + i);
}

extern "C" void kernel_launch(void* const* d_in, const int* in_sizes, int n_in,
                              void* d_out, int out_size, void* d_ws, size_t ws_size,
                              hipStream_t stream) {
    const f2v* in = (const f2v*)d_in[0];
    float* out = (float*)d_out;
    int n = in_sizes[0] / 2;   // B elements, each (x, y)

    int block = 256;
    int grid = (n + block - 1) / block;
    fw_energy_gad_kernel<<<grid, block, 0, stream>>>(in, out, n);
}